// Round 6
// baseline (129.924 us; speedup 1.0000x reference)
//
#include <hip/hip_runtime.h>

// Problem constants (match reference file)
constexpr int S      = 2048;          // sequence length (dim)
constexpr int B      = 8;
constexpr int EMB    = 1024;
constexpr int NROWS  = B * EMB;       // 8192 independent rows of length S
constexpr int WAVES_PER_BLOCK = 4;
constexpr int TPB    = WAVES_PER_BLOCK * 64;   // 256 threads
constexpr int CHUNK  = 64 * 4;        // elements per wave-iteration (lane*4)
constexpr int NITER  = S / CHUNK;     // 8

// Native clang vector: __builtin_nontemporal_* rejects HIP_vector_type (R5
// compile error) but accepts ext_vector_type.
typedef float vfloat4 __attribute__((ext_vector_type(4)));

// out[t] = A[t] + w1[t]*C[t] + bias[t]
//   A[t] = d0*A[t-1] + x[t]*w0[t]      (row-repeat term)
//   C[t] = d1*C[t-1] + x[t]            (col-repeat term, scaled by w1[t] at output)
// R3 lesson: EPL=8 + occupancy cap regressed (+7us); EPL=4 full-occupancy is best.
// R6: nontemporal (nt) loads on x / stores on out — stream-once data,
// bypassing L2 allocation is free-or-better. Roofline probe.
__global__ __launch_bounds__(TPB)
void crcl_scan_kernel(const float* __restrict__ x,
                      const float* __restrict__ weight,
                      const float* __restrict__ bias,
                      const float* __restrict__ dv,
                      float* __restrict__ out)
{
    const int wave = threadIdx.x >> 6;
    const int lane = threadIdx.x & 63;
    const int row  = blockIdx.x * WAVES_PER_BLOCK + wave;   // grid sized exactly

    // decay constants (clipped as in reference)
    const float d0 = fminf(fmaxf(dv[0], 0.9f), 1.0f);
    const float d1 = fminf(fmaxf(dv[1], 0.9f), 1.0f);

    const float d0_2 = d0 * d0, d0_3 = d0_2 * d0, d0_4 = d0_2 * d0_2;
    const float d1_2 = d1 * d1, d1_3 = d1_2 * d1, d1_4 = d1_2 * d1_2;

    // powers of d^4 by repeated squaring: d^8, d^16, d^32, d^64, d^128
    const float d0_8 = d0_4 * d0_4, d0_16 = d0_8 * d0_8, d0_32 = d0_16 * d0_16,
                d0_64 = d0_32 * d0_32, d0_128 = d0_64 * d0_64;
    const float d1_8 = d1_4 * d1_4, d1_16 = d1_8 * d1_8, d1_32 = d1_16 * d1_16,
                d1_64 = d1_32 * d1_32, d1_128 = d1_64 * d1_64;

    // lane-start decay d^(4*lane), exact product over set bits of lane
    float rl0 = 1.0f, rl1 = 1.0f;
    if (lane & 1)  { rl0 *= d0_4;   rl1 *= d1_4;   }
    if (lane & 2)  { rl0 *= d0_8;   rl1 *= d1_8;   }
    if (lane & 4)  { rl0 *= d0_16;  rl1 *= d1_16;  }
    if (lane & 8)  { rl0 *= d0_32;  rl1 *= d1_32;  }
    if (lane & 16) { rl0 *= d0_64;  rl1 *= d1_64;  }
    if (lane & 32) { rl0 *= d0_128; rl1 *= d1_128; }

    const float* __restrict__ xr   = x + (size_t)row * S;
    float*       __restrict__ outr = out + (size_t)row * S;
    const float* __restrict__ w0   = weight;        // weight[0][:]  (indexed by source s)
    const float* __restrict__ w1   = weight + S;    // weight[1][:]  (indexed by target t)

    float Acar = 0.0f, Ccar = 0.0f;   // scan state at position t0-1

    #pragma unroll
    for (int it = 0; it < NITER; ++it) {
        const int t0 = it * CHUNK + lane * 4;

        // x is stream-once: nontemporal load (nt flag, no L2 allocation)
        const vfloat4 xv = __builtin_nontemporal_load(
                               reinterpret_cast<const vfloat4*>(xr + t0));
        const float4 w0v = *reinterpret_cast<const float4*>(w0 + t0);
        const float4 w1v = *reinterpret_cast<const float4*>(w1 + t0);
        const float4 bv  = *reinterpret_cast<const float4*>(bias + t0);

        // lane-local serial scan over 4 elements (zero incoming carry)
        const float a0 = xv.x * w0v.x;
        const float a1 = fmaf(d0, a0, xv.y * w0v.y);
        const float a2 = fmaf(d0, a1, xv.z * w0v.z);
        const float a3 = fmaf(d0, a2, xv.w * w0v.w);
        const float c0 = xv.x;
        const float c1 = fmaf(d1, c0, xv.y);
        const float c2 = fmaf(d1, c1, xv.z);
        const float c3 = fmaf(d1, c2, xv.w);

        // wave-level inclusive scan of lane carries; ratio r = d^4
        float sA = a3, sC = c3;
        float q0 = d0_4, q1 = d1_4;
        #pragma unroll
        for (int off = 1; off < 64; off <<= 1) {
            const float tA = __shfl_up(sA, off);
            const float tC = __shfl_up(sC, off);
            if (lane >= off) {
                sA = fmaf(q0, tA, sA);
                sC = fmaf(q1, tC, sC);
            }
            q0 *= q0; q1 *= q1;
        }

        // exclusive prefix entering this lane (referenced at position lane*4 - 1)
        float eA = __shfl_up(sA, 1); if (lane == 0) eA = 0.0f;
        float eC = __shfl_up(sC, 1); if (lane == 0) eC = 0.0f;

        // add inter-iteration carry, decayed to this lane's start
        const float TA = fmaf(Acar, rl0, eA);
        const float TC = fmaf(Ccar, rl1, eC);

        // full scan values: A_k = a_k + TA * d^(k+1)
        const float A0 = fmaf(TA, d0,   a0);
        const float A1 = fmaf(TA, d0_2, a1);
        const float A2 = fmaf(TA, d0_3, a2);
        const float A3 = fmaf(TA, d0_4, a3);
        const float C0 = fmaf(TC, d1,   c0);
        const float C1 = fmaf(TC, d1_2, c1);
        const float C2 = fmaf(TC, d1_3, c2);
        const float C3 = fmaf(TC, d1_4, c3);

        vfloat4 ov;
        ov.x = fmaf(w1v.x, C0, A0) + bv.x;
        ov.y = fmaf(w1v.y, C1, A1) + bv.y;
        ov.z = fmaf(w1v.z, C2, A2) + bv.z;
        ov.w = fmaf(w1v.w, C3, A3) + bv.w;
        // out is write-once: nontemporal store (no L2 writeback allocation)
        __builtin_nontemporal_store(ov, reinterpret_cast<vfloat4*>(outr + t0));

        // carry = full value at last position of the chunk (lane 63, elem 3)
        Acar = __shfl(A3, 63);
        Ccar = __shfl(C3, 63);
    }
}

extern "C" void kernel_launch(void* const* d_in, const int* in_sizes, int n_in,
                              void* d_out, int out_size, void* d_ws, size_t ws_size,
                              hipStream_t stream) {
    const float* x      = (const float*)d_in[0];   // (B, EMB, S) f32
    const float* weight = (const float*)d_in[1];   // (2, S) f32
    const float* bias   = (const float*)d_in[2];   // (S,) f32
    const float* dv     = (const float*)d_in[3];   // (2, 1) f32
    // d_in[4] = index (unused), d_in[5] = recurrent (unused)
    float* out = (float*)d_out;

    const int grid = NROWS / WAVES_PER_BLOCK;      // 2048 blocks
    crcl_scan_kernel<<<grid, TPB, 0, stream>>>(x, weight, bias, dv, out);
}

// Round 7
// 122.584 us; speedup vs baseline: 1.0599x; 1.0599x over previous
//
#include <hip/hip_runtime.h>

// Problem constants (match reference file)
constexpr int S      = 2048;          // sequence length (dim)
constexpr int B      = 8;
constexpr int EMB    = 1024;
constexpr int NROWS  = B * EMB;       // 8192 independent rows of length S
constexpr int WAVES_PER_BLOCK = 4;
constexpr int TPB    = WAVES_PER_BLOCK * 64;   // 256 threads
constexpr int CHUNK  = 64 * 4;        // elements per wave-iteration (lane*4)
constexpr int NITER  = S / CHUNK;     // 8

// Native clang vector: __builtin_nontemporal_* rejects HIP_vector_type.
typedef float vfloat4 __attribute__((ext_vector_type(4)));

// out[t] = A[t] + w1[t]*C[t] + bias[t]
//   A[t] = d0*A[t-1] + x[t]*w0[t]      (row-repeat term)
//   C[t] = d1*C[t-1] + x[t]            (col-repeat term, scaled by w1[t] at output)
// Measured ladder: R2/R4 (cached ld/st) 127.1/127.8us; R3 (EPL=8+occ-cap)
// 133.9 (hurts); R6 (nt load+store) 129.9 (nt LOAD hurts: x is L3-warm from
// the harness d_in restore, nt bypasses that). R7: cached loads + nt store
// only — out is write-once, skipping write-allocate is free-or-better.
__global__ __launch_bounds__(TPB)
void crcl_scan_kernel(const float* __restrict__ x,
                      const float* __restrict__ weight,
                      const float* __restrict__ bias,
                      const float* __restrict__ dv,
                      float* __restrict__ out)
{
    const int wave = threadIdx.x >> 6;
    const int lane = threadIdx.x & 63;
    const int row  = blockIdx.x * WAVES_PER_BLOCK + wave;   // grid sized exactly

    // decay constants (clipped as in reference)
    const float d0 = fminf(fmaxf(dv[0], 0.9f), 1.0f);
    const float d1 = fminf(fmaxf(dv[1], 0.9f), 1.0f);

    const float d0_2 = d0 * d0, d0_3 = d0_2 * d0, d0_4 = d0_2 * d0_2;
    const float d1_2 = d1 * d1, d1_3 = d1_2 * d1, d1_4 = d1_2 * d1_2;

    // powers of d^4 by repeated squaring: d^8, d^16, d^32, d^64, d^128
    const float d0_8 = d0_4 * d0_4, d0_16 = d0_8 * d0_8, d0_32 = d0_16 * d0_16,
                d0_64 = d0_32 * d0_32, d0_128 = d0_64 * d0_64;
    const float d1_8 = d1_4 * d1_4, d1_16 = d1_8 * d1_8, d1_32 = d1_16 * d1_16,
                d1_64 = d1_32 * d1_32, d1_128 = d1_64 * d1_64;

    // lane-start decay d^(4*lane), exact product over set bits of lane
    float rl0 = 1.0f, rl1 = 1.0f;
    if (lane & 1)  { rl0 *= d0_4;   rl1 *= d1_4;   }
    if (lane & 2)  { rl0 *= d0_8;   rl1 *= d1_8;   }
    if (lane & 4)  { rl0 *= d0_16;  rl1 *= d1_16;  }
    if (lane & 8)  { rl0 *= d0_32;  rl1 *= d1_32;  }
    if (lane & 16) { rl0 *= d0_64;  rl1 *= d1_64;  }
    if (lane & 32) { rl0 *= d0_128; rl1 *= d1_128; }

    const float* __restrict__ xr   = x + (size_t)row * S;
    float*       __restrict__ outr = out + (size_t)row * S;
    const float* __restrict__ w0   = weight;        // weight[0][:]  (indexed by source s)
    const float* __restrict__ w1   = weight + S;    // weight[1][:]  (indexed by target t)

    float Acar = 0.0f, Ccar = 0.0f;   // scan state at position t0-1

    #pragma unroll
    for (int it = 0; it < NITER; ++it) {
        const int t0 = it * CHUNK + lane * 4;

        // cached load: x is L3-warm from the harness d_in restore
        const float4 xv  = *reinterpret_cast<const float4*>(xr + t0);
        const float4 w0v = *reinterpret_cast<const float4*>(w0 + t0);
        const float4 w1v = *reinterpret_cast<const float4*>(w1 + t0);
        const float4 bv  = *reinterpret_cast<const float4*>(bias + t0);

        // lane-local serial scan over 4 elements (zero incoming carry)
        const float a0 = xv.x * w0v.x;
        const float a1 = fmaf(d0, a0, xv.y * w0v.y);
        const float a2 = fmaf(d0, a1, xv.z * w0v.z);
        const float a3 = fmaf(d0, a2, xv.w * w0v.w);
        const float c0 = xv.x;
        const float c1 = fmaf(d1, c0, xv.y);
        const float c2 = fmaf(d1, c1, xv.z);
        const float c3 = fmaf(d1, c2, xv.w);

        // wave-level inclusive scan of lane carries; ratio r = d^4
        float sA = a3, sC = c3;
        float q0 = d0_4, q1 = d1_4;
        #pragma unroll
        for (int off = 1; off < 64; off <<= 1) {
            const float tA = __shfl_up(sA, off);
            const float tC = __shfl_up(sC, off);
            if (lane >= off) {
                sA = fmaf(q0, tA, sA);
                sC = fmaf(q1, tC, sC);
            }
            q0 *= q0; q1 *= q1;
        }

        // exclusive prefix entering this lane (referenced at position lane*4 - 1)
        float eA = __shfl_up(sA, 1); if (lane == 0) eA = 0.0f;
        float eC = __shfl_up(sC, 1); if (lane == 0) eC = 0.0f;

        // add inter-iteration carry, decayed to this lane's start
        const float TA = fmaf(Acar, rl0, eA);
        const float TC = fmaf(Ccar, rl1, eC);

        // full scan values: A_k = a_k + TA * d^(k+1)
        const float A0 = fmaf(TA, d0,   a0);
        const float A1 = fmaf(TA, d0_2, a1);
        const float A2 = fmaf(TA, d0_3, a2);
        const float A3 = fmaf(TA, d0_4, a3);
        const float C0 = fmaf(TC, d1,   c0);
        const float C1 = fmaf(TC, d1_2, c1);
        const float C2 = fmaf(TC, d1_3, c2);
        const float C3 = fmaf(TC, d1_4, c3);

        vfloat4 ov;
        ov.x = fmaf(w1v.x, C0, A0) + bv.x;
        ov.y = fmaf(w1v.y, C1, A1) + bv.y;
        ov.z = fmaf(w1v.z, C2, A2) + bv.z;
        ov.w = fmaf(w1v.w, C3, A3) + bv.w;
        // out is write-once: nontemporal store (skip write-allocate)
        __builtin_nontemporal_store(ov, reinterpret_cast<vfloat4*>(outr + t0));

        // carry = full value at last position of the chunk (lane 63, elem 3)
        Acar = __shfl(A3, 63);
        Ccar = __shfl(C3, 63);
    }
}

extern "C" void kernel_launch(void* const* d_in, const int* in_sizes, int n_in,
                              void* d_out, int out_size, void* d_ws, size_t ws_size,
                              hipStream_t stream) {
    const float* x      = (const float*)d_in[0];   // (B, EMB, S) f32
    const float* weight = (const float*)d_in[1];   // (2, S) f32
    const float* bias   = (const float*)d_in[2];   // (S,) f32
    const float* dv     = (const float*)d_in[3];   // (2, 1) f32
    // d_in[4] = index (unused), d_in[5] = recurrent (unused)
    float* out = (float*)d_out;

    const int grid = NROWS / WAVES_PER_BLOCK;      // 2048 blocks
    crcl_scan_kernel<<<grid, TPB, 0, stream>>>(x, weight, bias, dv, out);
}

// Round 9
// 120.942 us; speedup vs baseline: 1.0743x; 1.0136x over previous
//
#include <hip/hip_runtime.h>

// Problem constants (match reference file)
constexpr int S      = 2048;          // sequence length (dim)
constexpr int B      = 8;
constexpr int EMB    = 1024;
constexpr int NROWS  = B * EMB;       // 8192 independent rows of length S
constexpr int WAVES_PER_BLOCK = 4;
constexpr int TPB    = WAVES_PER_BLOCK * 64;   // 256 threads
constexpr int CHUNK  = 64 * 4;        // elements per wave-iteration (lane*4)
constexpr int NITER  = S / CHUNK;     // 8

// Native clang vector: __builtin_nontemporal_* rejects HIP_vector_type.
typedef float vfloat4 __attribute__((ext_vector_type(4)));

// out[t] = A[t] + w1[t]*C[t] + bias[t]
//   A[t] = d0*A[t-1] + x[t]*w0[t]      (row-repeat term)
//   C[t] = d1*C[t-1] + x[t]            (col-repeat term, scaled by w1[t] at output)
// Measured ladder: R2/R4 (cached ld/st) 127.1/127.8us; R3 (EPL=8+occ-cap)
// 133.9 (hurts); R6 (nt load+store) 129.9 (nt LOAD hurts: x is L3-warm from
// the harness d_in restore); R7 (cached loads + nt store) 122.6 (best —
// nt store keeps out's 64MiB from evicting L3-warm x).
// R9: A/A repro of R7 (R8 was an infra timeout) before any roofline claim.
__global__ __launch_bounds__(TPB)
void crcl_scan_kernel(const float* __restrict__ x,
                      const float* __restrict__ weight,
                      const float* __restrict__ bias,
                      const float* __restrict__ dv,
                      float* __restrict__ out)
{
    const int wave = threadIdx.x >> 6;
    const int lane = threadIdx.x & 63;
    const int row  = blockIdx.x * WAVES_PER_BLOCK + wave;   // grid sized exactly

    // decay constants (clipped as in reference)
    const float d0 = fminf(fmaxf(dv[0], 0.9f), 1.0f);
    const float d1 = fminf(fmaxf(dv[1], 0.9f), 1.0f);

    const float d0_2 = d0 * d0, d0_3 = d0_2 * d0, d0_4 = d0_2 * d0_2;
    const float d1_2 = d1 * d1, d1_3 = d1_2 * d1, d1_4 = d1_2 * d1_2;

    // powers of d^4 by repeated squaring: d^8, d^16, d^32, d^64, d^128
    const float d0_8 = d0_4 * d0_4, d0_16 = d0_8 * d0_8, d0_32 = d0_16 * d0_16,
                d0_64 = d0_32 * d0_32, d0_128 = d0_64 * d0_64;
    const float d1_8 = d1_4 * d1_4, d1_16 = d1_8 * d1_8, d1_32 = d1_16 * d1_16,
                d1_64 = d1_32 * d1_32, d1_128 = d1_64 * d1_64;

    // lane-start decay d^(4*lane), exact product over set bits of lane
    float rl0 = 1.0f, rl1 = 1.0f;
    if (lane & 1)  { rl0 *= d0_4;   rl1 *= d1_4;   }
    if (lane & 2)  { rl0 *= d0_8;   rl1 *= d1_8;   }
    if (lane & 4)  { rl0 *= d0_16;  rl1 *= d1_16;  }
    if (lane & 8)  { rl0 *= d0_32;  rl1 *= d1_32;  }
    if (lane & 16) { rl0 *= d0_64;  rl1 *= d1_64;  }
    if (lane & 32) { rl0 *= d0_128; rl1 *= d1_128; }

    const float* __restrict__ xr   = x + (size_t)row * S;
    float*       __restrict__ outr = out + (size_t)row * S;
    const float* __restrict__ w0   = weight;        // weight[0][:]  (indexed by source s)
    const float* __restrict__ w1   = weight + S;    // weight[1][:]  (indexed by target t)

    float Acar = 0.0f, Ccar = 0.0f;   // scan state at position t0-1

    #pragma unroll
    for (int it = 0; it < NITER; ++it) {
        const int t0 = it * CHUNK + lane * 4;

        // cached load: x is L3-warm from the harness d_in restore
        const float4 xv  = *reinterpret_cast<const float4*>(xr + t0);
        const float4 w0v = *reinterpret_cast<const float4*>(w0 + t0);
        const float4 w1v = *reinterpret_cast<const float4*>(w1 + t0);
        const float4 bv  = *reinterpret_cast<const float4*>(bias + t0);

        // lane-local serial scan over 4 elements (zero incoming carry)
        const float a0 = xv.x * w0v.x;
        const float a1 = fmaf(d0, a0, xv.y * w0v.y);
        const float a2 = fmaf(d0, a1, xv.z * w0v.z);
        const float a3 = fmaf(d0, a2, xv.w * w0v.w);
        const float c0 = xv.x;
        const float c1 = fmaf(d1, c0, xv.y);
        const float c2 = fmaf(d1, c1, xv.z);
        const float c3 = fmaf(d1, c2, xv.w);

        // wave-level inclusive scan of lane carries; ratio r = d^4
        float sA = a3, sC = c3;
        float q0 = d0_4, q1 = d1_4;
        #pragma unroll
        for (int off = 1; off < 64; off <<= 1) {
            const float tA = __shfl_up(sA, off);
            const float tC = __shfl_up(sC, off);
            if (lane >= off) {
                sA = fmaf(q0, tA, sA);
                sC = fmaf(q1, tC, sC);
            }
            q0 *= q0; q1 *= q1;
        }

        // exclusive prefix entering this lane (referenced at position lane*4 - 1)
        float eA = __shfl_up(sA, 1); if (lane == 0) eA = 0.0f;
        float eC = __shfl_up(sC, 1); if (lane == 0) eC = 0.0f;

        // add inter-iteration carry, decayed to this lane's start
        const float TA = fmaf(Acar, rl0, eA);
        const float TC = fmaf(Ccar, rl1, eC);

        // full scan values: A_k = a_k + TA * d^(k+1)
        const float A0 = fmaf(TA, d0,   a0);
        const float A1 = fmaf(TA, d0_2, a1);
        const float A2 = fmaf(TA, d0_3, a2);
        const float A3 = fmaf(TA, d0_4, a3);
        const float C0 = fmaf(TC, d1,   c0);
        const float C1 = fmaf(TC, d1_2, c1);
        const float C2 = fmaf(TC, d1_3, c2);
        const float C3 = fmaf(TC, d1_4, c3);

        vfloat4 ov;
        ov.x = fmaf(w1v.x, C0, A0) + bv.x;
        ov.y = fmaf(w1v.y, C1, A1) + bv.y;
        ov.z = fmaf(w1v.z, C2, A2) + bv.z;
        ov.w = fmaf(w1v.w, C3, A3) + bv.w;
        // out is write-once: nontemporal store (skip write-allocate,
        // don't evict L3-warm x)
        __builtin_nontemporal_store(ov, reinterpret_cast<vfloat4*>(outr + t0));

        // carry = full value at last position of the chunk (lane 63, elem 3)
        Acar = __shfl(A3, 63);
        Ccar = __shfl(C3, 63);
    }
}

extern "C" void kernel_launch(void* const* d_in, const int* in_sizes, int n_in,
                              void* d_out, int out_size, void* d_ws, size_t ws_size,
                              hipStream_t stream) {
    const float* x      = (const float*)d_in[0];   // (B, EMB, S) f32
    const float* weight = (const float*)d_in[1];   // (2, S) f32
    const float* bias   = (const float*)d_in[2];   // (S,) f32
    const float* dv     = (const float*)d_in[3];   // (2, 1) f32
    // d_in[4] = index (unused), d_in[5] = recurrent (unused)
    float* out = (float*)d_out;

    const int grid = NROWS / WAVES_PER_BLOCK;      // 2048 blocks
    crcl_scan_kernel<<<grid, TPB, 0, stream>>>(x, weight, bias, dv, out);
}